// Round 10
// baseline (839.298 us; speedup 1.0000x reference)
//
#include <hip/hip_runtime.h>
#include <math.h>

#define DM 768
#define NH 12
#define DK 64
#define DFF 3072
#define BB 2
#define SS 2048
#define NL 2

typedef __attribute__((ext_vector_type(8))) short short8;
typedef __attribute__((ext_vector_type(4))) float f32x4;

__device__ inline unsigned short f2bf(float f) {
    unsigned int u = __float_as_uint(f);
    u += 0x7fffu + ((u >> 16) & 1u);
    return (unsigned short)(u >> 16);
}
__device__ inline float bf2f(unsigned short h) {
    return __uint_as_float(((unsigned int)h) << 16);
}

#define GL16(g, l) __builtin_amdgcn_global_load_lds( \
    (const __attribute__((address_space(1))) void*)(g), \
    (__attribute__((address_space(3))) void*)(l), 16, 0, 0)

// ---------------- embed + positional (f32 + bf16 outputs) ----------------
__global__ __launch_bounds__(256) void embed_kernel(
    const int* __restrict__ toks, const float* __restrict__ emb,
    const float* __restrict__ pos, float* __restrict__ x,
    unsigned short* __restrict__ xb)
{
    int rs = blockIdx.x;
    int s = rs & (SS - 1);
    int tok = toks[rs];
    int t = threadIdx.x;
    const float* e = emb + (size_t)tok * DM;
    const float* p = pos + (size_t)s * DM;
    float* xr = x + (size_t)rs * DM;
    unsigned short* xbr = xb + (size_t)rs * DM;
#pragma unroll
    for (int i = 0; i < 3; ++i) {
        int c = t + 256 * i;
        float v = e[c] + p[c];
        xr[c] = v;
        xbr[c] = f2bf(v);
    }
}

// ---------------- batched weight transpose-convert, BOTH layers, 1 launch ---
__global__ __launch_bounds__(256) void prep_weights(
    const float* __restrict__ wq, const float* __restrict__ wk,
    const float* __restrict__ wv, const float* __restrict__ wo,
    const float* __restrict__ w1, const float* __restrict__ w2,
    unsigned short* __restrict__ wt)
{
    __shared__ float tile[32][33];
    int id = blockIdx.x;
    int l = id / 6912; id -= l * 6912;
    unsigned short* wtl = wt + (size_t)l * 7077888;
    const float* src; unsigned short* dst; int Kd, Nd, nt, kt;
    if (id < 2304) {
        int m = id / 576, r = id % 576;
        src = ((m == 0) ? wq : (m == 1) ? wk : (m == 2) ? wv : wo) + (size_t)l * DM * DM;
        dst = wtl + (size_t)m * 589824;
        Kd = 768; Nd = 768; nt = r / 24; kt = r % 24;
    } else if (id < 4608) {
        int r = id - 2304;
        src = w1 + (size_t)l * DM * DFF; dst = wtl + 2359296; Kd = 768; Nd = 3072;
        nt = r / 24; kt = r % 24;
    } else {
        int r = id - 4608;
        src = w2 + (size_t)l * DFF * DM; dst = wtl + 4718592; Kd = 3072; Nd = 768;
        nt = r / 96; kt = r % 96;
    }
    int n0 = nt * 32, k0 = kt * 32;
    int c = threadIdx.x & 31, rr = threadIdx.x >> 5;
#pragma unroll
    for (int i = 0; i < 32; i += 8)
        tile[rr + i][c] = src[(size_t)(k0 + rr + i) * Nd + n0 + c];
    __syncthreads();
#pragma unroll
    for (int i = 0; i < 32; i += 8)
        dst[(size_t)(n0 + rr + i) * Kd + k0 + c] = f2bf(tile[c][rr + i]);
}

// ---------------- V transpose: vb[b*S+s][DM] bf16 -> vt[b][DM][S] bf16 ------
__global__ __launch_bounds__(256) void transpose_v(
    const unsigned short* __restrict__ vb, unsigned short* __restrict__ vt)
{
    __shared__ unsigned short tile[32][33];
    int c0 = blockIdx.x * 32;
    int r0 = blockIdx.y * 32;
    int c = threadIdx.x & 31, rr = threadIdx.x >> 5;
#pragma unroll
    for (int i = 0; i < 32; i += 8)
        tile[rr + i][c] = vb[(size_t)(r0 + rr + i) * DM + c0 + c];
    __syncthreads();
    int b = r0 >> 11;
    int s0 = r0 & 2047;
#pragma unroll
    for (int i = 0; i < 32; i += 8)
        vt[((size_t)b * DM + c0 + rr + i) * SS + s0 + c] = tile[c][rr + i];
}

// ---------------- MFMA GEMM: C[M,N] = A[M,K](bf16) @ Bt[N,K](bf16)^T --------
// 128x128 tile, BK=64, swizzled LDS (conflict-free ds_read_b128), 4 waves.
// OUT_MODE: 0=f32 split-K partial (blockIdx.z slice), 1=bf16, 2=bf16+relu,
//           4=bf16 into 3 consecutive [4096][768] mats
template<int OUT_MODE>
__global__ __launch_bounds__(256) void gemm_bt(
    const unsigned short* __restrict__ A, const unsigned short* __restrict__ Bt,
    const float* __restrict__ bias, void* __restrict__ Cv,
    int K, int lda, int ldb, int ldc)
{
    __shared__ unsigned short As[128 * 64];   // 16KB, 128B rows, chunk-swizzled
    __shared__ unsigned short Bs[128 * 64];   // 16KB
    const int t = threadIdx.x;
    const int row0 = blockIdx.y * 128;
    const int col0 = blockIdx.x * 128;
    const int z = (OUT_MODE == 0) ? blockIdx.z : 0;
    if (OUT_MODE == 0) { A += (size_t)z * K; Bt += (size_t)z * K; }
    const int lane = t & 63, wid = t >> 6;
    const int wr = wid >> 1, wc = wid & 1;
    const int half = lane >> 4, lr = lane & 15;
    f32x4 acc[4][4] = {};

    for (int k0 = 0; k0 < K; k0 += 64) {
        // stage A,B tiles: pre-swizzled source chunk, linear LDS dest (rule #21)
#pragma unroll
        for (int r_ = 0; r_ < 4; ++r_) {
            int o_ = r_ * 4096 + t * 16;
            int row_ = o_ >> 7;                 // 0..127
            int cp_ = (o_ >> 4) & 7;            // 16B chunk within 128B row
            int gk_ = (cp_ ^ (row_ & 7)) << 3;  // swizzled k-offset (ushorts)
            GL16(A + (size_t)(row0 + row_) * lda + k0 + gk_, (char*)As + o_);
            GL16(Bt + (size_t)(col0 + row_) * ldb + k0 + gk_, (char*)Bs + o_);
        }
        __syncthreads();
#pragma unroll
        for (int kk = 0; kk < 2; ++kk) {
            short8 a_[4], b_[4];
#pragma unroll
            for (int m = 0; m < 4; ++m) {
                int row_ = wr * 64 + m * 16 + lr;
                a_[m] = *(const short8*)&As[row_ * 64 + (((kk * 4 + half) ^ (row_ & 7)) << 3)];
            }
#pragma unroll
            for (int n = 0; n < 4; ++n) {
                int row_ = wc * 64 + n * 16 + lr;
                b_[n] = *(const short8*)&Bs[row_ * 64 + (((kk * 4 + half) ^ (row_ & 7)) << 3)];
            }
#pragma unroll
            for (int m = 0; m < 4; ++m)
#pragma unroll
                for (int n = 0; n < 4; ++n)
                    acc[m][n] = __builtin_amdgcn_mfma_f32_16x16x32_bf16(a_[m], b_[n], acc[m][n], 0, 0, 0);
        }
        __syncthreads();
    }

#pragma unroll
    for (int m = 0; m < 4; ++m) {
#pragma unroll
        for (int n = 0; n < 4; ++n) {
            const int cidx = col0 + wc * 64 + n * 16 + lr;
            const float bv = bias ? bias[cidx] : 0.0f;
#pragma unroll
            for (int j = 0; j < 4; ++j) {
                const int r = row0 + wr * 64 + m * 16 + half * 4 + j;
                float v = acc[m][n][j] + bv;
                if (OUT_MODE == 2) v = fmaxf(v, 0.0f);
                if (OUT_MODE == 0) {
                    ((float*)Cv)[((size_t)z * 4096 + r) * ldc + cidx] = v;
                } else if (OUT_MODE == 4) {
                    int mi = (cidx >= 1536) ? 2 : (cidx >= 768 ? 1 : 0);
                    int cl = cidx - mi * 768;
                    ((unsigned short*)Cv)[((size_t)mi * 4096 + r) * 768 + cl] = f2bf(v);
                } else {
                    ((unsigned short*)Cv)[(size_t)r * ldc + cidx] = f2bf(v);
                }
            }
        }
    }
}

// ---------------- attn pass A as standalone kernel: row-sum reciprocals -----
// 1536 blocks (6/CU), qblk=32, NO LDS tiles, NO per-kt barriers. K fragments
// per-lane from L2 (r9-proven). Writes rinv[bh*SS + qpos].
__global__ __launch_bounds__(256) void attn_sums(
    const unsigned short* __restrict__ qg, const unsigned short* __restrict__ kg,
    const int* __restrict__ amask, float* __restrict__ rsum)
{
    __shared__ float red[128];
    const int t = threadIdx.x;
    const int id = blockIdx.x;              // 0..1535
    const int xcd = id & 7, idx = id >> 3;  // idx 0..191
    const int bh = xcd * 3 + (idx >> 6);    // 3 heads per XCD
    const int qt = idx & 63;
    const int b = bh / NH, h = bh % NH;
    const int q0 = qt * 32;
    const int lane = t & 63, w = t >> 6;
    const int half = lane >> 4, lr = lane & 15;
    const int* am = amask + b * SS;

    const unsigned short* qbase = qg + ((size_t)b * SS + q0 + lr) * DM + h * DK + half * 8;
    short8 afq[2][2];
#pragma unroll
    for (int m = 0; m < 2; ++m) {
        afq[m][0] = *(const short8*)(qbase + m * 16 * DM);
        afq[m][1] = *(const short8*)(qbase + m * 16 * DM + 32);
    }
    const unsigned short* Kg = kg + (size_t)b * SS * DM + h * DK;

    float vsum[2][4] = {};
    for (int kt = 0; kt < 16; ++kt) {
#pragma unroll
        for (int nn = 0; nn < 2; ++nn) {
            const int kpos = kt * 128 + w * 32 + nn * 16 + lr;
            const unsigned short* kr = Kg + (size_t)kpos * DM;
            short8 bk0 = *(const short8*)(kr + half * 8);
            short8 bk1 = *(const short8*)(kr + 32 + half * 8);
            const bool pad = (am[kpos] == 0);
#pragma unroll
            for (int m = 0; m < 2; ++m) {
                f32x4 s = {};
                s = __builtin_amdgcn_mfma_f32_16x16x32_bf16(afq[m][0], bk0, s, 0, 0, 0);
                s = __builtin_amdgcn_mfma_f32_16x16x32_bf16(afq[m][1], bk1, s, 0, 0, 0);
#pragma unroll
                for (int j = 0; j < 4; ++j) {
                    int qpos = q0 + m * 16 + half * 4 + j;
                    if (pad || (kpos > qpos))   // FAITHFUL: keep where pad||future
                        vsum[m][j] += __expf(0.125f * s[j]);
                }
            }
        }
    }
#pragma unroll
    for (int m = 0; m < 2; ++m)
#pragma unroll
        for (int j = 0; j < 4; ++j) {
            vsum[m][j] += __shfl_xor(vsum[m][j], 1, 64);
            vsum[m][j] += __shfl_xor(vsum[m][j], 2, 64);
            vsum[m][j] += __shfl_xor(vsum[m][j], 4, 64);
            vsum[m][j] += __shfl_xor(vsum[m][j], 8, 64);
        }
    if (lr == 0) {
#pragma unroll
        for (int m = 0; m < 2; ++m)
#pragma unroll
            for (int j = 0; j < 4; ++j)
                red[w * 32 + m * 16 + half * 4 + j] = vsum[m][j];
    }
    __syncthreads();
    if (t < 32) {
        float rs = red[t] + red[32 + t] + red[64 + t] + red[96 + t];
        rsum[(size_t)bh * SS + q0 + t] = (rs > 0.0f) ? 1.0f / rs : 0.0f;
    }
}

// ---------------- attn pass B: normalized E -> P + PV, 32KB LDS ------------
// 768 blocks (3/CU), qblk=64; V single-buffered (stage hides under QK phase);
// rinv from attn_sums; setprio around PV MFMA (T5); cached P-writes (r8).
__global__ __launch_bounds__(256) void attn_pv(
    const unsigned short* __restrict__ qg, const unsigned short* __restrict__ kg,
    const unsigned short* __restrict__ vt, const int* __restrict__ amask,
    const float* __restrict__ rsumG, float* __restrict__ attnL,
    unsigned short* __restrict__ cb)
{
    __shared__ unsigned short Vs[64 * 128];   // 16KB [d][s], swizzled
    __shared__ unsigned short Es[64 * 128];   // 16KB [qrow][kcol], swizzled

    const int t = threadIdx.x;
    const int id = blockIdx.x;              // 0..767
    const int xcd = id & 7, idx = id >> 3;  // idx 0..95
    const int bh = xcd * 3 + (idx >> 5);    // 3 heads per XCD
    const int qt = idx & 31;
    const int b = bh / NH, h = bh % NH;
    const int q0 = qt * 64;
    const int lane = t & 63, w = t >> 6;
    const int half = lane >> 4, lr = lane & 15;
    const int* am = amask + b * SS;

    const unsigned short* qbase = qg + ((size_t)b * SS + q0 + lr) * DM + h * DK + half * 8;
    short8 afq[4][2];
#pragma unroll
    for (int m = 0; m < 4; ++m) {
        afq[m][0] = *(const short8*)(qbase + m * 16 * DM);
        afq[m][1] = *(const short8*)(qbase + m * 16 * DM + 32);
    }
    float rinv[4][4];
#pragma unroll
    for (int m = 0; m < 4; ++m)
#pragma unroll
        for (int j = 0; j < 4; ++j)
            rinv[m][j] = rsumG[(size_t)bh * SS + q0 + m * 16 + half * 4 + j];

    const unsigned short* Kg = kg + (size_t)b * SS * DM + h * DK;
    const unsigned short* Vg = vt + ((size_t)b * DM + h * DK) * SS;

#define STAGE_V(kt) { \
    _Pragma("unroll") \
    for (int r_ = 0; r_ < 4; ++r_) { \
        int o_ = r_ * 4096 + t * 16; \
        int d_ = o_ >> 8; \
        int cp_ = (o_ >> 4) & 15; \
        GL16(Vg + (size_t)d_ * SS + (kt) * 128 + ((cp_ ^ (d_ & 7)) << 3), (char*)Vs + o_); \
    } }

    f32x4 ctxa[4] = {};
    float* ab = attnL + ((size_t)bh * SS + q0) * SS;
    for (int kt = 0; kt < 16; ++kt) {
        STAGE_V(kt);   // single buffer; latency hidden under QK/exp phase

        // K fragments per-lane from L2 + QK + exp + Es writes
#pragma unroll
        for (int nn = 0; nn < 2; ++nn) {
            const int krl = w * 32 + nn * 16 + lr;
            const int kpos = kt * 128 + krl;
            const unsigned short* kr = Kg + (size_t)kpos * DM;
            short8 bk0 = *(const short8*)(kr + half * 8);
            short8 bk1 = *(const short8*)(kr + 32 + half * 8);
            const bool pad = (am[kpos] == 0);
#pragma unroll
            for (int m = 0; m < 4; ++m) {
                f32x4 s = {};
                s = __builtin_amdgcn_mfma_f32_16x16x32_bf16(afq[m][0], bk0, s, 0, 0, 0);
                s = __builtin_amdgcn_mfma_f32_16x16x32_bf16(afq[m][1], bk1, s, 0, 0, 0);
#pragma unroll
                for (int j = 0; j < 4; ++j) {
                    int row = m * 16 + half * 4 + j;
                    int qpos = q0 + row;
                    bool keep = pad || (kpos > qpos);
                    float e = keep ? __expf(0.125f * s[j]) * rinv[m][j] : 0.0f;
                    *((unsigned short*)((char*)Es + row * 256 + ((krl * 2) ^ ((row & 7) << 4)))) = f2bf(e);
                }
            }
        }
        // V staged + Es visible; prev-kt P-stores have had a full phase to drain
        asm volatile("s_waitcnt vmcnt(0) lgkmcnt(0)" ::: "memory");
        __builtin_amdgcn_s_barrier();

        // PV: ctx += E[64x128] @ V[128x64]; wave w owns d-cols w*16..+15
        __builtin_amdgcn_s_setprio(1);
#pragma unroll
        for (int ks = 0; ks < 4; ++ks) {
            const int dl = w * 16 + lr;
            const int cv = ks * 4 + half;
            short8 bv = *(const short8*)((const char*)Vs + dl * 256 + ((cv ^ (dl & 7)) << 4));
#pragma unroll
            for (int m = 0; m < 4; ++m) {
                short8 ae = *(const short8*)((const char*)Es + (m * 16 + lr) * 256 +
                                             ((ks * 64 + half * 16) ^ ((lr & 7) << 4)));
                ctxa[m] = __builtin_amdgcn_mfma_f32_16x16x32_bf16(ae, bv, ctxa[m], 0, 0, 0);
            }
        }
        __builtin_amdgcn_s_setprio(0);

        // P-write: 256 threads cover 64 rows x 4 chunk-groups (32 f32 each),
        // CACHED stores (r7 lesson: NT partial-line stores = 2.3x HBM write amp)
        {
            const int prow = t >> 2, pg = t & 3;
            const char* erow = (const char*)Es + prow * 256;
            const int swz = (prow & 7) << 4;
            float* drow = ab + (size_t)prow * SS + kt * 128;
#pragma unroll
            for (int c = 0; c < 4; ++c) {
                const int chunk = pg * 4 + c;
                short8 ev = *(const short8*)(erow + ((chunk * 16) ^ swz));
                float* dst = drow + chunk * 8;
                f32x4 o0, o1;
                o0[0] = bf2f((unsigned short)ev[0]); o0[1] = bf2f((unsigned short)ev[1]);
                o0[2] = bf2f((unsigned short)ev[2]); o0[3] = bf2f((unsigned short)ev[3]);
                o1[0] = bf2f((unsigned short)ev[4]); o1[1] = bf2f((unsigned short)ev[5]);
                o1[2] = bf2f((unsigned short)ev[6]); o1[3] = bf2f((unsigned short)ev[7]);
                *(f32x4*)dst = o0;
                *(f32x4*)(dst + 4) = o1;
            }
        }
        // all waves done reading Vs/Es before next kt overwrites them
        __builtin_amdgcn_s_barrier();
    }

    // ctx write (already normalized)
#pragma unroll
    for (int m = 0; m < 4; ++m)
#pragma unroll
        for (int j = 0; j < 4; ++j) {
            int row = m * 16 + half * 4 + j;
            cb[((size_t)b * SS + q0 + row) * DM + h * DK + w * 16 + lr] = f2bf(ctxa[m][j]);
        }
#undef STAGE_V
}

// ------- residual add (two f32 split-K partials + opt bias) + layernorm ----
__global__ __launch_bounds__(256) void add_ln_kernel(
    const float* __restrict__ p0, const float* __restrict__ p1,
    const float* __restrict__ bias, const float* __restrict__ xin,
    const float* __restrict__ g, const float* __restrict__ bta,
    float* __restrict__ xout, unsigned short* __restrict__ xbout)
{
    int row = blockIdx.x;
    int t = threadIdx.x;
    const float* a0 = p0 + (size_t)row * DM;
    const float* a1 = p1 + (size_t)row * DM;
    const float* xr = xin + (size_t)row * DM;
    float* orow = xout + (size_t)row * DM;
    unsigned short* obr = xbout + (size_t)row * DM;
    __shared__ float red[256];
    float v[3];
    float sum = 0.0f;
#pragma unroll
    for (int i = 0; i < 3; ++i) {
        int c = t + 256 * i;
        v[i] = a0[c] + a1[c] + xr[c] + (bias ? bias[c] : 0.0f);
        sum += v[i];
    }
    red[t] = sum;
    __syncthreads();
    for (int s = 128; s > 0; s >>= 1) {
        if (t < s) red[t] += red[t + s];
        __syncthreads();
    }
    float mean = red[0] * (1.0f / DM);
    __syncthreads();
    float sq = 0.0f;
#pragma unroll
    for (int i = 0; i < 3; ++i) {
        float d = v[i] - mean;
        sq += d * d;
    }
    red[t] = sq;
    __syncthreads();
    for (int s = 128; s > 0; s >>= 1) {
        if (t < s) red[t] += red[t + s];
        __syncthreads();
    }
    float inv = 1.0f / sqrtf(red[0] * (1.0f / DM) + 1e-5f);
#pragma unroll
    for (int i = 0; i < 3; ++i) {
        int c = t + 256 * i;
        float ov = (v[i] - mean) * inv * g[c] + bta[c];
        orow[c] = ov;
        obr[c] = f2bf(ov);
    }
}

extern "C" void kernel_launch(void* const* d_in, const int* in_sizes, int n_in,
                              void* d_out, int out_size, void* d_ws, size_t ws_size,
                              hipStream_t stream)
{
    const int*   toks  = (const int*)d_in[0];
    const int*   amask = (const int*)d_in[1];
    const float* emb   = (const float*)d_in[2];
    const float* pos   = (const float*)d_in[3];
    const float* wq    = (const float*)d_in[4];
    const float* wk    = (const float*)d_in[5];
    const float* wv    = (const float*)d_in[6];
    const float* wo    = (const float*)d_in[7];
    const float* ln1g  = (const float*)d_in[8];
    const float* ln1b  = (const float*)d_in[9];
    const float* w1    = (const float*)d_in[10];
    const float* b1    = (const float*)d_in[11];
    const float* w2    = (const float*)d_in[12];
    const float* b2    = (const float*)d_in[13];
    const float* ln2g  = (const float*)d_in[14];
    const float* ln2b  = (const float*)d_in[15];

    float* out = (float*)d_out;
    char*  wsb = (char*)d_ws;

    const size_t ROWS = (size_t)BB * SS;                 // 4096
    const size_t XSZ  = ROWS * DM;                       // 3,145,728
    const size_t ATTN_L = (size_t)BB * NH * SS * SS;     // 100,663,296

    float*          x    = (float*)(wsb);                          // 12.58 MB
    unsigned short* xb   = (unsigned short*)(wsb + 12582912);      // 6.29 MB
    unsigned short* qb   = (unsigned short*)(wsb + 18874368);      // 6.29 MB (QKV out 0)
    unsigned short* kbuf = (unsigned short*)(wsb + 25165824);      // 6.29 MB (QKV out 1)
    unsigned short* vb   = (unsigned short*)(wsb + 31457280);      // 6.29 MB (QKV out 2)
    unsigned short* cb   = (unsigned short*)(wsb + 37748736);      // 6.29 MB
    float*          p0   = (float*)(wsb + 44040192);               // 25.17 MB (2 split-K slabs)
    float*          rsum = (float*)(wsb + 44040192);               // 196 KB, aliases p0 (free during attn)
    unsigned short* vt   = (unsigned short*)(wsb + 69206016);      // aliases ffb
    unsigned short* ffb  = (unsigned short*)(wsb + 69206016);      // 25.17 MB
    unsigned short* wt   = (unsigned short*)(wsb + 94371840);      // 28.31 MB (both layers)

    float* attn_out = out + XSZ;

    embed_kernel<<<ROWS, 256, 0, stream>>>(toks, emb, pos, x, xb);
    prep_weights<<<13824, 256, 0, stream>>>(wq, wk, wv, wo, w1, w2, wt);

    for (int l = 0; l < NL; ++l) {
        unsigned short* QKVT = wt + (size_t)l * 7077888;
        unsigned short* WOT  = QKVT + 1769472;
        unsigned short* W1T  = QKVT + 2359296;
        unsigned short* W2T  = QKVT + 4718592;

        // merged QKV projection: N=2304 -> qb | kbuf | vb (row-major bf16)
        gemm_bt<4><<<dim3(18, 32), 256, 0, stream>>>(xb, QKVT, nullptr, qb, DM, DM, DM, DM);
        transpose_v<<<dim3(24, 128), 256, 0, stream>>>(vb, vt);

        float* attnL = attn_out + (size_t)l * ATTN_L;
        attn_sums<<<1536, 256, 0, stream>>>(qb, kbuf, amask, rsum);
        attn_pv<<<768, 256, 0, stream>>>(qb, kbuf, vt, amask, rsum, attnL, cb);

        // output projection (split-K=2, f32 partials) + LN1
        gemm_bt<0><<<dim3(6, 32, 2), 256, 0, stream>>>(cb, WOT, nullptr, p0, 384, DM, DM, DM);
        add_ln_kernel<<<ROWS, 256, 0, stream>>>(p0, p0 + XSZ, nullptr, x,
                                                ln1g + l * DM, ln1b + l * DM, x, xb);

        // FFN: W1+relu, W2 (split-K=2) + LN2 (bias b2 folded into LN)
        gemm_bt<2><<<dim3(24, 32), 256, 0, stream>>>(xb, W1T, b1 + (size_t)l * DFF, ffb, DM, DM, DM, DFF);
        gemm_bt<0><<<dim3(6, 32, 2), 256, 0, stream>>>(ffb, W2T, nullptr, p0, 1536, DFF, DFF, DM);

        float* xdst = (l == NL - 1) ? out : x;
        add_ln_kernel<<<ROWS, 256, 0, stream>>>(p0, p0 + XSZ, b2 + (size_t)l * DM, x,
                                                ln2g + l * DM, ln2b + l * DM, xdst, xb);
    }
}

// Round 11
// 715.542 us; speedup vs baseline: 1.1730x; 1.1730x over previous
//
#include <hip/hip_runtime.h>
#include <math.h>

#define DM 768
#define NH 12
#define DK 64
#define DFF 3072
#define BB 2
#define SS 2048
#define NL 2

typedef __attribute__((ext_vector_type(8))) short short8;
typedef __attribute__((ext_vector_type(4))) float f32x4;
typedef __attribute__((ext_vector_type(2))) unsigned int u32x2;

__device__ inline unsigned short f2bf(float f) {
    unsigned int u = __float_as_uint(f);
    u += 0x7fffu + ((u >> 16) & 1u);
    return (unsigned short)(u >> 16);
}
__device__ inline float bf2f(unsigned short h) {
    return __uint_as_float(((unsigned int)h) << 16);
}

#define GL16(g, l) __builtin_amdgcn_global_load_lds( \
    (const __attribute__((address_space(1))) void*)(g), \
    (__attribute__((address_space(3))) void*)(l), 16, 0, 0)

// ---------------- embed + positional (f32 + bf16 outputs) ----------------
__global__ __launch_bounds__(256) void embed_kernel(
    const int* __restrict__ toks, const float* __restrict__ emb,
    const float* __restrict__ pos, float* __restrict__ x,
    unsigned short* __restrict__ xb)
{
    int rs = blockIdx.x;
    int s = rs & (SS - 1);
    int tok = toks[rs];
    int t = threadIdx.x;
    const float* e = emb + (size_t)tok * DM;
    const float* p = pos + (size_t)s * DM;
    float* xr = x + (size_t)rs * DM;
    unsigned short* xbr = xb + (size_t)rs * DM;
#pragma unroll
    for (int i = 0; i < 3; ++i) {
        int c = t + 256 * i;
        float v = e[c] + p[c];
        xr[c] = v;
        xbr[c] = f2bf(v);
    }
}

// ---------------- batched weight transpose-convert, BOTH layers, 1 launch ---
__global__ __launch_bounds__(256) void prep_weights(
    const float* __restrict__ wq, const float* __restrict__ wk,
    const float* __restrict__ wv, const float* __restrict__ wo,
    const float* __restrict__ w1, const float* __restrict__ w2,
    unsigned short* __restrict__ wt)
{
    __shared__ float tile[32][33];
    int id = blockIdx.x;
    int l = id / 6912; id -= l * 6912;
    unsigned short* wtl = wt + (size_t)l * 7077888;
    const float* src; unsigned short* dst; int Kd, Nd, nt, kt;
    if (id < 2304) {
        int m = id / 576, r = id % 576;
        src = ((m == 0) ? wq : (m == 1) ? wk : (m == 2) ? wv : wo) + (size_t)l * DM * DM;
        dst = wtl + (size_t)m * 589824;
        Kd = 768; Nd = 768; nt = r / 24; kt = r % 24;
    } else if (id < 4608) {
        int r = id - 2304;
        src = w1 + (size_t)l * DM * DFF; dst = wtl + 2359296; Kd = 768; Nd = 3072;
        nt = r / 24; kt = r % 24;
    } else {
        int r = id - 4608;
        src = w2 + (size_t)l * DFF * DM; dst = wtl + 4718592; Kd = 3072; Nd = 768;
        nt = r / 96; kt = r % 96;
    }
    int n0 = nt * 32, k0 = kt * 32;
    int c = threadIdx.x & 31, rr = threadIdx.x >> 5;
#pragma unroll
    for (int i = 0; i < 32; i += 8)
        tile[rr + i][c] = src[(size_t)(k0 + rr + i) * Nd + n0 + c];
    __syncthreads();
#pragma unroll
    for (int i = 0; i < 32; i += 8)
        dst[(size_t)(n0 + rr + i) * Kd + k0 + c] = f2bf(tile[c][rr + i]);
}

// ---------------- V transpose: vb[b*S+s][DM] bf16 -> vt[b][DM][S] bf16 ------
__global__ __launch_bounds__(256) void transpose_v(
    const unsigned short* __restrict__ vb, unsigned short* __restrict__ vt)
{
    __shared__ unsigned short tile[32][33];
    int c0 = blockIdx.x * 32;
    int r0 = blockIdx.y * 32;
    int c = threadIdx.x & 31, rr = threadIdx.x >> 5;
#pragma unroll
    for (int i = 0; i < 32; i += 8)
        tile[rr + i][c] = vb[(size_t)(r0 + rr + i) * DM + c0 + c];
    __syncthreads();
    int b = r0 >> 11;
    int s0 = r0 & 2047;
#pragma unroll
    for (int i = 0; i < 32; i += 8)
        vt[((size_t)b * DM + c0 + rr + i) * SS + s0 + c] = tile[c][rr + i];
}

// ---------------- MFMA GEMM: C[M,N] = A[M,K](bf16) @ Bt[N,K](bf16)^T --------
// 128x128 tile, BK=64, swizzled LDS (conflict-free ds_read_b128), 4 waves.
// OUT_MODE: 0=f32 split-K partial (blockIdx.z slice), 1=bf16, 2=bf16+relu,
//           4=bf16 into 3 consecutive [4096][768] mats
template<int OUT_MODE>
__global__ __launch_bounds__(256) void gemm_bt(
    const unsigned short* __restrict__ A, const unsigned short* __restrict__ Bt,
    const float* __restrict__ bias, void* __restrict__ Cv,
    int K, int lda, int ldb, int ldc)
{
    __shared__ unsigned short As[128 * 64];   // 16KB, 128B rows, chunk-swizzled
    __shared__ unsigned short Bs[128 * 64];   // 16KB
    const int t = threadIdx.x;
    const int row0 = blockIdx.y * 128;
    const int col0 = blockIdx.x * 128;
    const int z = (OUT_MODE == 0) ? blockIdx.z : 0;
    if (OUT_MODE == 0) { A += (size_t)z * K; Bt += (size_t)z * K; }
    const int lane = t & 63, wid = t >> 6;
    const int wr = wid >> 1, wc = wid & 1;
    const int half = lane >> 4, lr = lane & 15;
    f32x4 acc[4][4] = {};

    for (int k0 = 0; k0 < K; k0 += 64) {
        // stage A,B tiles: pre-swizzled source chunk, linear LDS dest (rule #21)
#pragma unroll
        for (int r_ = 0; r_ < 4; ++r_) {
            int o_ = r_ * 4096 + t * 16;
            int row_ = o_ >> 7;                 // 0..127
            int cp_ = (o_ >> 4) & 7;            // 16B chunk within 128B row
            int gk_ = (cp_ ^ (row_ & 7)) << 3;  // swizzled k-offset (ushorts)
            GL16(A + (size_t)(row0 + row_) * lda + k0 + gk_, (char*)As + o_);
            GL16(Bt + (size_t)(col0 + row_) * ldb + k0 + gk_, (char*)Bs + o_);
        }
        __syncthreads();
#pragma unroll
        for (int kk = 0; kk < 2; ++kk) {
            short8 a_[4], b_[4];
#pragma unroll
            for (int m = 0; m < 4; ++m) {
                int row_ = wr * 64 + m * 16 + lr;
                a_[m] = *(const short8*)&As[row_ * 64 + (((kk * 4 + half) ^ (row_ & 7)) << 3)];
            }
#pragma unroll
            for (int n = 0; n < 4; ++n) {
                int row_ = wc * 64 + n * 16 + lr;
                b_[n] = *(const short8*)&Bs[row_ * 64 + (((kk * 4 + half) ^ (row_ & 7)) << 3)];
            }
#pragma unroll
            for (int m = 0; m < 4; ++m)
#pragma unroll
                for (int n = 0; n < 4; ++n)
                    acc[m][n] = __builtin_amdgcn_mfma_f32_16x16x32_bf16(a_[m], b_[n], acc[m][n], 0, 0, 0);
        }
        __syncthreads();
    }

#pragma unroll
    for (int m = 0; m < 4; ++m) {
#pragma unroll
        for (int n = 0; n < 4; ++n) {
            const int cidx = col0 + wc * 64 + n * 16 + lr;
            const float bv = bias ? bias[cidx] : 0.0f;
#pragma unroll
            for (int j = 0; j < 4; ++j) {
                const int r = row0 + wr * 64 + m * 16 + half * 4 + j;
                float v = acc[m][n][j] + bv;
                if (OUT_MODE == 2) v = fmaxf(v, 0.0f);
                if (OUT_MODE == 0) {
                    ((float*)Cv)[((size_t)z * 4096 + r) * ldc + cidx] = v;
                } else if (OUT_MODE == 4) {
                    int mi = (cidx >= 1536) ? 2 : (cidx >= 768 ? 1 : 0);
                    int cl = cidx - mi * 768;
                    ((unsigned short*)Cv)[((size_t)mi * 4096 + r) * 768 + cl] = f2bf(v);
                } else {
                    ((unsigned short*)Cv)[(size_t)r * ldc + cidx] = f2bf(v);
                }
            }
        }
    }
}

// ---------------- fused attention v7: swapped QK (r9 base) ------------------
// r9 structure (740us best): 768 blocks 3/CU, K direct from L2, dbuf V with
// counted vmcnt(8), barrier-free pass A, cached P-writes.
// NEW: mfma(K,Q) instead of mfma(Q,K) -> lane holds E[kpos..+3][q=lr]:
//  - E-store: 32x ds_write_b16 -> 8x ds_write_b64 (packed), 4 words/bank min
//  - rinv/vsum indexed by q=lr only: 16 VGPR -> 4
//  - s_setprio(1) around PV MFMA cluster (T5, attn-positive)
__global__ __launch_bounds__(256) void attn_fused(
    const unsigned short* __restrict__ qg, const unsigned short* __restrict__ kg,
    const unsigned short* __restrict__ vt, const int* __restrict__ amask,
    float* __restrict__ attnL, unsigned short* __restrict__ cb)
{
    __shared__ unsigned short Vs[2][64 * 128];   // 2x16KB [d][s], swizzled
    __shared__ unsigned short Es[64 * 128];      // 16KB [qrow][kcol]; aliased as red scratch

    const int t = threadIdx.x;
    const int id = blockIdx.x;              // 0..767
    const int xcd = id & 7, idx = id >> 3;  // idx 0..95
    const int bh = xcd * 3 + (idx >> 5);    // 24 heads, 3 per XCD
    const int qt = idx & 31;
    const int b = bh / NH, h = bh % NH;
    const int q0 = qt * 64;
    const int lane = t & 63, w = t >> 6;
    const int half = lane >> 4, lr = lane & 15;
    const int* am = amask + b * SS;

    // Q fragments (dual-use A/B layout): rows q0+m*16+lr, k = half*8 (+32)
    const unsigned short* qbase = qg + ((size_t)b * SS + q0 + lr) * DM + h * DK + half * 8;
    short8 afq[4][2];
#pragma unroll
    for (int m = 0; m < 4; ++m) {
        afq[m][0] = *(const short8*)(qbase + m * 16 * DM);
        afq[m][1] = *(const short8*)(qbase + m * 16 * DM + 32);
    }

    const unsigned short* Kg = kg + (size_t)b * SS * DM + h * DK;
    const unsigned short* Vg = vt + ((size_t)b * DM + h * DK) * SS;

#define STAGE_V(kt, buf) { \
    _Pragma("unroll") \
    for (int r_ = 0; r_ < 4; ++r_) { \
        int o_ = r_ * 4096 + t * 16; \
        int d_ = o_ >> 8; \
        int cp_ = (o_ >> 4) & 15; \
        GL16(Vg + (size_t)d_ * SS + (kt) * 128 + ((cp_ ^ (d_ & 7)) << 3), (char*)Vs[buf] + o_); \
    } }

    // ======== pass A: row sums — barrier-free, swapped QK =================
    // mfma(K,Q): lane gets C[kpos=kb+half*4+j][q=lr] -> vsum indexed by q only
    float vsum[4] = {};
    for (int kt = 0; kt < 16; ++kt) {
#pragma unroll
        for (int nn = 0; nn < 2; ++nn) {
            const int kb = kt * 128 + w * 32 + nn * 16;
            const unsigned short* kr = Kg + (size_t)(kb + lr) * DM;
            short8 ak0 = *(const short8*)(kr + half * 8);
            short8 ak1 = *(const short8*)(kr + 32 + half * 8);
            const int pd0 = am[kb + half * 4 + 0];
            const int pd1 = am[kb + half * 4 + 1];
            const int pd2 = am[kb + half * 4 + 2];
            const int pd3 = am[kb + half * 4 + 3];
#pragma unroll
            for (int m = 0; m < 4; ++m) {
                f32x4 s = {};
                s = __builtin_amdgcn_mfma_f32_16x16x32_bf16(ak0, afq[m][0], s, 0, 0, 0);
                s = __builtin_amdgcn_mfma_f32_16x16x32_bf16(ak1, afq[m][1], s, 0, 0, 0);
                const int qpos = q0 + m * 16 + lr;
                // FAITHFUL: keep where pad||future
                if (pd0 == 0 || kb + half * 4 + 0 > qpos) vsum[m] += __expf(0.125f * s[0]);
                if (pd1 == 0 || kb + half * 4 + 1 > qpos) vsum[m] += __expf(0.125f * s[1]);
                if (pd2 == 0 || kb + half * 4 + 2 > qpos) vsum[m] += __expf(0.125f * s[2]);
                if (pd3 == 0 || kb + half * 4 + 3 > qpos) vsum[m] += __expf(0.125f * s[3]);
            }
        }
    }
    // prefetch pass-B V tile 0 while reducing
    STAGE_V(0, 0);
    __syncthreads();

    // reduce across half-groups (lanes ^16, ^32), then across waves via Es scratch
    float* red = (float*)Es;     // [0..255]: per-wave sums, [256..319]: inv
#pragma unroll
    for (int m = 0; m < 4; ++m) {
        vsum[m] += __shfl_xor(vsum[m], 16, 64);
        vsum[m] += __shfl_xor(vsum[m], 32, 64);
    }
    if (half == 0) {
#pragma unroll
        for (int m = 0; m < 4; ++m) red[w * 64 + m * 16 + lr] = vsum[m];
    }
    __syncthreads();
    if (t < 64) {
        float rs = red[t] + red[64 + t] + red[128 + t] + red[192 + t];
        red[256 + t] = (rs > 0.0f) ? 1.0f / rs : 0.0f;
    }
    __syncthreads();
    float rinv_[4];
#pragma unroll
    for (int m = 0; m < 4; ++m) rinv_[m] = red[256 + m * 16 + lr];
    __syncthreads();   // rinv in regs; Es area may now be overwritten

    // ================= pass B: normalized E -> P + PV =================
    f32x4 ctxa[4] = {};
    float* ab = attnL + ((size_t)bh * SS + q0) * SS;
    for (int kt = 0; kt < 16; ++kt) {
        if (kt == 0) {
            asm volatile("s_waitcnt vmcnt(0)" ::: "memory");
        } else {
            asm volatile("s_waitcnt vmcnt(8)" ::: "memory");  // drain 4 V loads; P-stores stay in flight
        }
        __builtin_amdgcn_s_barrier();

        // K fragments + mask FIRST (so compiler's K-use wait leaves V prefetch in flight)
        short8 ak[2][2];
        int pd[2][4];
#pragma unroll
        for (int nn = 0; nn < 2; ++nn) {
            const int kb = kt * 128 + w * 32 + nn * 16;
            const unsigned short* kr = Kg + (size_t)(kb + lr) * DM;
            ak[nn][0] = *(const short8*)(kr + half * 8);
            ak[nn][1] = *(const short8*)(kr + 32 + half * 8);
#pragma unroll
            for (int j = 0; j < 4; ++j) pd[nn][j] = am[kb + half * 4 + j];
        }
        __builtin_amdgcn_sched_barrier(0);
        if (kt < 15) STAGE_V(kt + 1, (kt + 1) & 1);

#pragma unroll
        for (int nn = 0; nn < 2; ++nn) {
            const int kb = kt * 128 + w * 32 + nn * 16;
            const int colb = (w * 32 + nn * 16 + half * 4) * 2;  // byte col, pre-swizzle
#pragma unroll
            for (int m = 0; m < 4; ++m) {
                f32x4 s = {};
                s = __builtin_amdgcn_mfma_f32_16x16x32_bf16(ak[nn][0], afq[m][0], s, 0, 0, 0);
                s = __builtin_amdgcn_mfma_f32_16x16x32_bf16(ak[nn][1], afq[m][1], s, 0, 0, 0);
                const int qpos = q0 + m * 16 + lr;
                float e0 = (pd[nn][0] == 0 || kb + half * 4 + 0 > qpos) ? __expf(0.125f * s[0]) * rinv_[m] : 0.0f;
                float e1 = (pd[nn][1] == 0 || kb + half * 4 + 1 > qpos) ? __expf(0.125f * s[1]) * rinv_[m] : 0.0f;
                float e2 = (pd[nn][2] == 0 || kb + half * 4 + 2 > qpos) ? __expf(0.125f * s[2]) * rinv_[m] : 0.0f;
                float e3 = (pd[nn][3] == 0 || kb + half * 4 + 3 > qpos) ? __expf(0.125f * s[3]) * rinv_[m] : 0.0f;
                u32x2 pk;
                pk[0] = ((unsigned int)f2bf(e1) << 16) | f2bf(e0);
                pk[1] = ((unsigned int)f2bf(e3) << 16) | f2bf(e2);
                const int row = m * 16 + lr;
                *(u32x2*)((char*)Es + row * 256 + (colb ^ ((lr & 7) << 4))) = pk;
            }
        }
        asm volatile("s_waitcnt lgkmcnt(0)" ::: "memory");   // E-writes visible
        __builtin_amdgcn_s_barrier();

        // PV: ctx += E[64x128] @ V[128x64]; wave w owns d-cols w*16..+15
        const char* vbuf = (const char*)Vs[kt & 1];
        __builtin_amdgcn_s_setprio(1);
#pragma unroll
        for (int ks = 0; ks < 4; ++ks) {
            const int dl = w * 16 + lr;
            const int cv = ks * 4 + half;
            short8 bv = *(const short8*)(vbuf + dl * 256 + ((cv ^ (dl & 7)) << 4));
#pragma unroll
            for (int m = 0; m < 4; ++m) {
                short8 ae = *(const short8*)((const char*)Es + (m * 16 + lr) * 256 +
                                             ((ks * 64 + half * 16) ^ ((lr & 7) << 4)));
                ctxa[m] = __builtin_amdgcn_mfma_f32_16x16x32_bf16(ae, bv, ctxa[m], 0, 0, 0);
            }
        }
        __builtin_amdgcn_s_setprio(0);

        // P-write: 256 threads cover 64 rows x 4 chunk-groups (32 f32 each),
        // CACHED stores (r7 lesson: NT partial-line stores = 2.3x HBM write amp)
        {
            const int prow = t >> 2, pg = t & 3;
            const char* erow = (const char*)Es + prow * 256;
            const int swz = (prow & 7) << 4;
            float* drow = ab + (size_t)prow * SS + kt * 128;
#pragma unroll
            for (int c = 0; c < 4; ++c) {
                const int chunk = pg * 4 + c;
                short8 ev = *(const short8*)(erow + ((chunk * 16) ^ swz));
                float* dst = drow + chunk * 8;
                f32x4 o0, o1;
                o0[0] = bf2f((unsigned short)ev[0]); o0[1] = bf2f((unsigned short)ev[1]);
                o0[2] = bf2f((unsigned short)ev[2]); o0[3] = bf2f((unsigned short)ev[3]);
                o1[0] = bf2f((unsigned short)ev[4]); o1[1] = bf2f((unsigned short)ev[5]);
                o1[2] = bf2f((unsigned short)ev[6]); o1[3] = bf2f((unsigned short)ev[7]);
                *(f32x4*)dst = o0;
                *(f32x4*)(dst + 4) = o1;
            }
        }
    }

    // ctx write (already normalized)
#pragma unroll
    for (int m = 0; m < 4; ++m)
#pragma unroll
        for (int j = 0; j < 4; ++j) {
            int row = m * 16 + half * 4 + j;
            cb[((size_t)b * SS + q0 + row) * DM + h * DK + w * 16 + lr] = f2bf(ctxa[m][j]);
        }
#undef STAGE_V
}

// ------- residual add (two f32 split-K partials + opt bias) + layernorm ----
__global__ __launch_bounds__(256) void add_ln_kernel(
    const float* __restrict__ p0, const float* __restrict__ p1,
    const float* __restrict__ bias, const float* __restrict__ xin,
    const float* __restrict__ g, const float* __restrict__ bta,
    float* __restrict__ xout, unsigned short* __restrict__ xbout)
{
    int row = blockIdx.x;
    int t = threadIdx.x;
    const float* a0 = p0 + (size_t)row * DM;
    const float* a1 = p1 + (size_t)row * DM;
    const float* xr = xin + (size_t)row * DM;
    float* orow = xout + (size_t)row * DM;
    unsigned short* obr = xbout + (size_t)row * DM;
    __shared__ float red[256];
    float v[3];
    float sum = 0.0f;
#pragma unroll
    for (int i = 0; i < 3; ++i) {
        int c = t + 256 * i;
        v[i] = a0[c] + a1[c] + xr[c] + (bias ? bias[c] : 0.0f);
        sum += v[i];
    }
    red[t] = sum;
    __syncthreads();
    for (int s = 128; s > 0; s >>= 1) {
        if (t < s) red[t] += red[t + s];
        __syncthreads();
    }
    float mean = red[0] * (1.0f / DM);
    __syncthreads();
    float sq = 0.0f;
#pragma unroll
    for (int i = 0; i < 3; ++i) {
        float d = v[i] - mean;
        sq += d * d;
    }
    red[t] = sq;
    __syncthreads();
    for (int s = 128; s > 0; s >>= 1) {
        if (t < s) red[t] += red[t + s];
        __syncthreads();
    }
    float inv = 1.0f / sqrtf(red[0] * (1.0f / DM) + 1e-5f);
#pragma unroll
    for (int i = 0; i < 3; ++i) {
        int c = t + 256 * i;
        float ov = (v[i] - mean) * inv * g[c] + bta[c];
        orow[c] = ov;
        obr[c] = f2bf(ov);
    }
}

extern "C" void kernel_launch(void* const* d_in, const int* in_sizes, int n_in,
                              void* d_out, int out_size, void* d_ws, size_t ws_size,
                              hipStream_t stream)
{
    const int*   toks  = (const int*)d_in[0];
    const int*   amask = (const int*)d_in[1];
    const float* emb   = (const float*)d_in[2];
    const float* pos   = (const float*)d_in[3];
    const float* wq    = (const float*)d_in[4];
    const float* wk    = (const float*)d_in[5];
    const float* wv    = (const float*)d_in[6];
    const float* wo    = (const float*)d_in[7];
    const float* ln1g  = (const float*)d_in[8];
    const float* ln1b  = (const float*)d_in[9];
    const float* w1    = (const float*)d_in[10];
    const float* b1    = (const float*)d_in[11];
    const float* w2    = (const float*)d_in[12];
    const float* b2    = (const float*)d_in[13];
    const float* ln2g  = (const float*)d_in[14];
    const float* ln2b  = (const float*)d_in[15];

    float* out = (float*)d_out;
    char*  wsb = (char*)d_ws;

    const size_t ROWS = (size_t)BB * SS;                 // 4096
    const size_t XSZ  = ROWS * DM;                       // 3,145,728
    const size_t ATTN_L = (size_t)BB * NH * SS * SS;     // 100,663,296

    float*          x    = (float*)(wsb);                          // 12.58 MB
    unsigned short* xb   = (unsigned short*)(wsb + 12582912);      // 6.29 MB
    unsigned short* qb   = (unsigned short*)(wsb + 18874368);      // 6.29 MB (QKV out 0)
    unsigned short* kbuf = (unsigned short*)(wsb + 25165824);      // 6.29 MB (QKV out 1)
    unsigned short* vb   = (unsigned short*)(wsb + 31457280);      // 6.29 MB (QKV out 2)
    unsigned short* cb   = (unsigned short*)(wsb + 37748736);      // 6.29 MB
    float*          p0   = (float*)(wsb + 44040192);               // 25.17 MB (2 split-K slabs)
    unsigned short* vt   = (unsigned short*)(wsb + 69206016);      // aliases ffb
    unsigned short* ffb  = (unsigned short*)(wsb + 69206016);      // 25.17 MB
    unsigned short* wt   = (unsigned short*)(wsb + 94371840);      // 28.31 MB (both layers)

    float* attn_out = out + XSZ;

    embed_kernel<<<ROWS, 256, 0, stream>>>(toks, emb, pos, x, xb);
    prep_weights<<<13824, 256, 0, stream>>>(wq, wk, wv, wo, w1, w2, wt);

    for (int l = 0; l < NL; ++l) {
        unsigned short* QKVT = wt + (size_t)l * 7077888;
        unsigned short* WOT  = QKVT + 1769472;
        unsigned short* W1T  = QKVT + 2359296;
        unsigned short* W2T  = QKVT + 4718592;

        // merged QKV projection: N=2304 -> qb | kbuf | vb (row-major bf16)
        gemm_bt<4><<<dim3(18, 32), 256, 0, stream>>>(xb, QKVT, nullptr, qb, DM, DM, DM, DM);
        transpose_v<<<dim3(24, 128), 256, 0, stream>>>(vb, vt);

        float* attnL = attn_out + (size_t)l * ATTN_L;
        attn_fused<<<768, 256, 0, stream>>>(qb, kbuf, vt, amask, attnL, cb);

        // output projection (split-K=2, f32 partials) + LN1
        gemm_bt<0><<<dim3(6, 32, 2), 256, 0, stream>>>(cb, WOT, nullptr, p0, 384, DM, DM, DM);
        add_ln_kernel<<<ROWS, 256, 0, stream>>>(p0, p0 + XSZ, nullptr, x,
                                                ln1g + l * DM, ln1b + l * DM, x, xb);

        // FFN: W1+relu, W2 (split-K=2) + LN2 (bias b2 folded into LN)
        gemm_bt<2><<<dim3(24, 32), 256, 0, stream>>>(xb, W1T, b1 + (size_t)l * DFF, ffb, DM, DM, DM, DFF);
        gemm_bt<0><<<dim3(6, 32, 2), 256, 0, stream>>>(ffb, W2T, nullptr, p0, 1536, DFF, DFF, DM);

        float* xdst = (l == NL - 1) ? out : x;
        add_ln_kernel<<<ROWS, 256, 0, stream>>>(p0, p0 + XSZ, b2 + (size_t)l * DM, x,
                                                ln2g + l * DM, ln2b + l * DM, xdst, xb);
    }
}

// Round 12
// 711.095 us; speedup vs baseline: 1.1803x; 1.0063x over previous
//
#include <hip/hip_runtime.h>
#include <math.h>

#define DM 768
#define NH 12
#define DK 64
#define DFF 3072
#define BB 2
#define SS 2048
#define NL 2

typedef __attribute__((ext_vector_type(8))) short short8;
typedef __attribute__((ext_vector_type(4))) float f32x4;
typedef __attribute__((ext_vector_type(2))) unsigned int u32x2;

__device__ inline unsigned short f2bf(float f) {
    unsigned int u = __float_as_uint(f);
    u += 0x7fffu + ((u >> 16) & 1u);
    return (unsigned short)(u >> 16);
}
__device__ inline float bf2f(unsigned short h) {
    return __uint_as_float(((unsigned int)h) << 16);
}

#define GL16(g, l) __builtin_amdgcn_global_load_lds( \
    (const __attribute__((address_space(1))) void*)(g), \
    (__attribute__((address_space(3))) void*)(l), 16, 0, 0)

// ---------------- embed + positional (f32 + bf16 outputs) ----------------
__global__ __launch_bounds__(256) void embed_kernel(
    const int* __restrict__ toks, const float* __restrict__ emb,
    const float* __restrict__ pos, float* __restrict__ x,
    unsigned short* __restrict__ xb)
{
    int rs = blockIdx.x;
    int s = rs & (SS - 1);
    int tok = toks[rs];
    int t = threadIdx.x;
    const float* e = emb + (size_t)tok * DM;
    const float* p = pos + (size_t)s * DM;
    float* xr = x + (size_t)rs * DM;
    unsigned short* xbr = xb + (size_t)rs * DM;
#pragma unroll
    for (int i = 0; i < 3; ++i) {
        int c = t + 256 * i;
        float v = e[c] + p[c];
        xr[c] = v;
        xbr[c] = f2bf(v);
    }
}

// ---------------- batched weight transpose-convert, BOTH layers, 1 launch ---
__global__ __launch_bounds__(256) void prep_weights(
    const float* __restrict__ wq, const float* __restrict__ wk,
    const float* __restrict__ wv, const float* __restrict__ wo,
    const float* __restrict__ w1, const float* __restrict__ w2,
    unsigned short* __restrict__ wt)
{
    __shared__ float tile[32][33];
    int id = blockIdx.x;
    int l = id / 6912; id -= l * 6912;
    unsigned short* wtl = wt + (size_t)l * 7077888;
    const float* src; unsigned short* dst; int Kd, Nd, nt, kt;
    if (id < 2304) {
        int m = id / 576, r = id % 576;
        src = ((m == 0) ? wq : (m == 1) ? wk : (m == 2) ? wv : wo) + (size_t)l * DM * DM;
        dst = wtl + (size_t)m * 589824;
        Kd = 768; Nd = 768; nt = r / 24; kt = r % 24;
    } else if (id < 4608) {
        int r = id - 2304;
        src = w1 + (size_t)l * DM * DFF; dst = wtl + 2359296; Kd = 768; Nd = 3072;
        nt = r / 24; kt = r % 24;
    } else {
        int r = id - 4608;
        src = w2 + (size_t)l * DFF * DM; dst = wtl + 4718592; Kd = 3072; Nd = 768;
        nt = r / 96; kt = r % 96;
    }
    int n0 = nt * 32, k0 = kt * 32;
    int c = threadIdx.x & 31, rr = threadIdx.x >> 5;
#pragma unroll
    for (int i = 0; i < 32; i += 8)
        tile[rr + i][c] = src[(size_t)(k0 + rr + i) * Nd + n0 + c];
    __syncthreads();
#pragma unroll
    for (int i = 0; i < 32; i += 8)
        dst[(size_t)(n0 + rr + i) * Kd + k0 + c] = f2bf(tile[c][rr + i]);
}

// ---------------- V transpose: vb[b*S+s][DM] bf16 -> vt[b][DM][S] bf16 ------
__global__ __launch_bounds__(256) void transpose_v(
    const unsigned short* __restrict__ vb, unsigned short* __restrict__ vt)
{
    __shared__ unsigned short tile[32][33];
    int c0 = blockIdx.x * 32;
    int r0 = blockIdx.y * 32;
    int c = threadIdx.x & 31, rr = threadIdx.x >> 5;
#pragma unroll
    for (int i = 0; i < 32; i += 8)
        tile[rr + i][c] = vb[(size_t)(r0 + rr + i) * DM + c0 + c];
    __syncthreads();
    int b = r0 >> 11;
    int s0 = r0 & 2047;
#pragma unroll
    for (int i = 0; i < 32; i += 8)
        vt[((size_t)b * DM + c0 + rr + i) * SS + s0 + c] = tile[c][rr + i];
}

// ---------------- MFMA GEMM: C[M,N] = A[M,K](bf16) @ Bt[N,K](bf16)^T --------
// 128x128 tile, BK=64, swizzled LDS (conflict-free ds_read_b128), 4 waves.
// OUT_MODE: 0=f32 split-K partial (blockIdx.z slice), 1=bf16, 2=bf16+relu,
//           4=bf16 into 3 consecutive [4096][768] mats
template<int OUT_MODE>
__global__ __launch_bounds__(256) void gemm_bt(
    const unsigned short* __restrict__ A, const unsigned short* __restrict__ Bt,
    const float* __restrict__ bias, void* __restrict__ Cv,
    int K, int lda, int ldb, int ldc)
{
    __shared__ unsigned short As[128 * 64];   // 16KB, 128B rows, chunk-swizzled
    __shared__ unsigned short Bs[128 * 64];   // 16KB
    const int t = threadIdx.x;
    const int row0 = blockIdx.y * 128;
    const int col0 = blockIdx.x * 128;
    const int z = (OUT_MODE == 0) ? blockIdx.z : 0;
    if (OUT_MODE == 0) { A += (size_t)z * K; Bt += (size_t)z * K; }
    const int lane = t & 63, wid = t >> 6;
    const int wr = wid >> 1, wc = wid & 1;
    const int half = lane >> 4, lr = lane & 15;
    f32x4 acc[4][4] = {};

    for (int k0 = 0; k0 < K; k0 += 64) {
        // stage A,B tiles: pre-swizzled source chunk, linear LDS dest (rule #21)
#pragma unroll
        for (int r_ = 0; r_ < 4; ++r_) {
            int o_ = r_ * 4096 + t * 16;
            int row_ = o_ >> 7;                 // 0..127
            int cp_ = (o_ >> 4) & 7;            // 16B chunk within 128B row
            int gk_ = (cp_ ^ (row_ & 7)) << 3;  // swizzled k-offset (ushorts)
            GL16(A + (size_t)(row0 + row_) * lda + k0 + gk_, (char*)As + o_);
            GL16(Bt + (size_t)(col0 + row_) * ldb + k0 + gk_, (char*)Bs + o_);
        }
        __syncthreads();
#pragma unroll
        for (int kk = 0; kk < 2; ++kk) {
            short8 a_[4], b_[4];
#pragma unroll
            for (int m = 0; m < 4; ++m) {
                int row_ = wr * 64 + m * 16 + lr;
                a_[m] = *(const short8*)&As[row_ * 64 + (((kk * 4 + half) ^ (row_ & 7)) << 3)];
            }
#pragma unroll
            for (int n = 0; n < 4; ++n) {
                int row_ = wc * 64 + n * 16 + lr;
                b_[n] = *(const short8*)&Bs[row_ * 64 + (((kk * 4 + half) ^ (row_ & 7)) << 3)];
            }
#pragma unroll
            for (int m = 0; m < 4; ++m)
#pragma unroll
                for (int n = 0; n < 4; ++n)
                    acc[m][n] = __builtin_amdgcn_mfma_f32_16x16x32_bf16(a_[m], b_[n], acc[m][n], 0, 0, 0);
        }
        __syncthreads();
    }

#pragma unroll
    for (int m = 0; m < 4; ++m) {
#pragma unroll
        for (int n = 0; n < 4; ++n) {
            const int cidx = col0 + wc * 64 + n * 16 + lr;
            const float bv = bias ? bias[cidx] : 0.0f;
#pragma unroll
            for (int j = 0; j < 4; ++j) {
                const int r = row0 + wr * 64 + m * 16 + half * 4 + j;
                float v = acc[m][n][j] + bv;
                if (OUT_MODE == 2) v = fmaxf(v, 0.0f);
                if (OUT_MODE == 0) {
                    ((float*)Cv)[((size_t)z * 4096 + r) * ldc + cidx] = v;
                } else if (OUT_MODE == 4) {
                    int mi = (cidx >= 1536) ? 2 : (cidx >= 768 ? 1 : 0);
                    int cl = cidx - mi * 768;
                    ((unsigned short*)Cv)[((size_t)mi * 4096 + r) * 768 + cl] = f2bf(v);
                } else {
                    ((unsigned short*)Cv)[(size_t)r * ldc + cidx] = f2bf(v);
                }
            }
        }
    }
}

// ---------------- fused attention v8: r11 + latency-exposure cuts -----------
// r11 base (715us): swapped QK, 768 blocks 3/CU, K direct from L2, dbuf V,
// cached P-writes. NEW:
//  1. mask -> 256B bitfield in LDS (8 global gathers/window -> 1 LDS bcast)
//  2. K-fragment prefetch for kt+1 issued after kt's QK (lands under PV)
//  3. top-of-window wait: compiler fence only (compiler emits counted waits
//     at first use; P-stores keep riding)
//  4. pass A: unroll x2 + branchless accumulate
__global__ __launch_bounds__(256) void attn_fused(
    const unsigned short* __restrict__ qg, const unsigned short* __restrict__ kg,
    const unsigned short* __restrict__ vt, const int* __restrict__ amask,
    float* __restrict__ attnL, unsigned short* __restrict__ cb)
{
    __shared__ unsigned short Vs[2][64 * 128];   // 2x16KB [d][s], swizzled
    __shared__ unsigned short Es[64 * 128];      // 16KB [qrow][kcol]; aliased as red scratch
    __shared__ unsigned int mbits[64];           // 2048-bit pad mask (bit=1 <=> am==0)

    const int t = threadIdx.x;
    const int id = blockIdx.x;              // 0..767
    const int xcd = id & 7, idx = id >> 3;  // idx 0..95
    const int bh = xcd * 3 + (idx >> 5);    // 24 heads, 3 per XCD
    const int qt = idx & 31;
    const int b = bh / NH, h = bh % NH;
    const int q0 = qt * 64;
    const int lane = t & 63, w = t >> 6;
    const int half = lane >> 4, lr = lane & 15;
    const int* am = amask + b * SS;

    // pack pad mask into bits once
    if (t < 64) {
        unsigned int m_ = 0;
#pragma unroll
        for (int i = 0; i < 32; ++i)
            m_ |= (unsigned int)(am[t * 32 + i] == 0) << i;
        mbits[t] = m_;
    }

    // Q fragments (dual-use A/B layout): rows q0+m*16+lr, k = half*8 (+32)
    const unsigned short* qbase = qg + ((size_t)b * SS + q0 + lr) * DM + h * DK + half * 8;
    short8 afq[4][2];
#pragma unroll
    for (int m = 0; m < 4; ++m) {
        afq[m][0] = *(const short8*)(qbase + m * 16 * DM);
        afq[m][1] = *(const short8*)(qbase + m * 16 * DM + 32);
    }

    const unsigned short* Kg = kg + (size_t)b * SS * DM + h * DK;
    const unsigned short* Vg = vt + ((size_t)b * DM + h * DK) * SS;

#define STAGE_V(kt, buf) { \
    _Pragma("unroll") \
    for (int r_ = 0; r_ < 4; ++r_) { \
        int o_ = r_ * 4096 + t * 16; \
        int d_ = o_ >> 8; \
        int cp_ = (o_ >> 4) & 15; \
        GL16(Vg + (size_t)d_ * SS + (kt) * 128 + ((cp_ ^ (d_ & 7)) << 3), (char*)Vs[buf] + o_); \
    } }

    __syncthreads();   // mbits visible

    // ======== pass A: row sums — barrier-free, swapped QK, unroll x2 ========
    float vsum[4] = {};
#pragma unroll 2
    for (int kt = 0; kt < 16; ++kt) {
#pragma unroll
        for (int nn = 0; nn < 2; ++nn) {
            const int kb = kt * 128 + w * 32 + nn * 16;
            const unsigned int mw = mbits[kb >> 5];
            const int bit0 = (kb & 31) + half * 4;
            const unsigned short* kr = Kg + (size_t)(kb + lr) * DM;
            short8 ak0 = *(const short8*)(kr + half * 8);
            short8 ak1 = *(const short8*)(kr + 32 + half * 8);
#pragma unroll
            for (int m = 0; m < 4; ++m) {
                f32x4 s = {};
                s = __builtin_amdgcn_mfma_f32_16x16x32_bf16(ak0, afq[m][0], s, 0, 0, 0);
                s = __builtin_amdgcn_mfma_f32_16x16x32_bf16(ak1, afq[m][1], s, 0, 0, 0);
                const int qpos = q0 + m * 16 + lr;
#pragma unroll
                for (int j = 0; j < 4; ++j) {
                    bool keep = ((mw >> (bit0 + j)) & 1u) || (kb + half * 4 + j > qpos);
                    vsum[m] += keep ? __expf(0.125f * s[j]) : 0.0f;
                }
            }
        }
    }
    // prefetch pass-B V tile 0 + K frags for kt=0 while reducing
    STAGE_V(0, 0);
    short8 ak[2][2], akn[2][2];
#pragma unroll
    for (int nn = 0; nn < 2; ++nn) {
        const unsigned short* kr = Kg + (size_t)(w * 32 + nn * 16 + lr) * DM;
        ak[nn][0] = *(const short8*)(kr + half * 8);
        ak[nn][1] = *(const short8*)(kr + 32 + half * 8);
    }
    __syncthreads();

    // reduce across half-groups (lanes ^16, ^32), then across waves via Es scratch
    float* red = (float*)Es;     // [0..255]: per-wave sums, [256..319]: inv
#pragma unroll
    for (int m = 0; m < 4; ++m) {
        vsum[m] += __shfl_xor(vsum[m], 16, 64);
        vsum[m] += __shfl_xor(vsum[m], 32, 64);
    }
    if (half == 0) {
#pragma unroll
        for (int m = 0; m < 4; ++m) red[w * 64 + m * 16 + lr] = vsum[m];
    }
    __syncthreads();
    if (t < 64) {
        float rs = red[t] + red[64 + t] + red[128 + t] + red[192 + t];
        red[256 + t] = (rs > 0.0f) ? 1.0f / rs : 0.0f;
    }
    __syncthreads();
    float rinv_[4];
#pragma unroll
    for (int m = 0; m < 4; ++m) rinv_[m] = red[256 + m * 16 + lr];
    __syncthreads();   // rinv in regs; Es area may now be overwritten

    // ================= pass B: normalized E -> P + PV =================
    f32x4 ctxa[4] = {};
    float* ab = attnL + ((size_t)bh * SS + q0) * SS;
    for (int kt = 0; kt < 16; ++kt) {
        asm volatile("" ::: "memory");       // fence only; no vmem drain
        __builtin_amdgcn_s_barrier();        // Es free (prev P-write reads done)

        // QK phase with prefetched ak; E packed to Es
#pragma unroll
        for (int nn = 0; nn < 2; ++nn) {
            const int kb = kt * 128 + w * 32 + nn * 16;
            const unsigned int mw = mbits[kb >> 5];
            const int bit0 = (kb & 31) + half * 4;
            const int colb = (w * 32 + nn * 16 + half * 4) * 2;  // byte col
#pragma unroll
            for (int m = 0; m < 4; ++m) {
                f32x4 s = {};
                s = __builtin_amdgcn_mfma_f32_16x16x32_bf16(ak[nn][0], afq[m][0], s, 0, 0, 0);
                s = __builtin_amdgcn_mfma_f32_16x16x32_bf16(ak[nn][1], afq[m][1], s, 0, 0, 0);
                const int qpos = q0 + m * 16 + lr;
                float e0 = (((mw >> (bit0 + 0)) & 1u) || (kb + half * 4 + 0 > qpos)) ? __expf(0.125f * s[0]) * rinv_[m] : 0.0f;
                float e1 = (((mw >> (bit0 + 1)) & 1u) || (kb + half * 4 + 1 > qpos)) ? __expf(0.125f * s[1]) * rinv_[m] : 0.0f;
                float e2 = (((mw >> (bit0 + 2)) & 1u) || (kb + half * 4 + 2 > qpos)) ? __expf(0.125f * s[2]) * rinv_[m] : 0.0f;
                float e3 = (((mw >> (bit0 + 3)) & 1u) || (kb + half * 4 + 3 > qpos)) ? __expf(0.125f * s[3]) * rinv_[m] : 0.0f;
                u32x2 pk;
                pk[0] = ((unsigned int)f2bf(e1) << 16) | f2bf(e0);
                pk[1] = ((unsigned int)f2bf(e3) << 16) | f2bf(e2);
                const int row = m * 16 + lr;
                *(u32x2*)((char*)Es + row * 256 + (colb ^ ((lr & 7) << 4))) = pk;
            }
        }
        // prefetch next window's K frags + V tile (land during PV + next QK)
        if (kt < 15) {
#pragma unroll
            for (int nn = 0; nn < 2; ++nn) {
                const unsigned short* kr = Kg + (size_t)((kt + 1) * 128 + w * 32 + nn * 16 + lr) * DM;
                akn[nn][0] = *(const short8*)(kr + half * 8);
                akn[nn][1] = *(const short8*)(kr + 32 + half * 8);
            }
            STAGE_V(kt + 1, (kt + 1) & 1);
        }
        asm volatile("s_waitcnt lgkmcnt(0)" ::: "memory");   // E-writes visible
        __builtin_amdgcn_s_barrier();

        // PV: ctx += E[64x128] @ V[128x64]; wave w owns d-cols w*16..+15
        const char* vbuf = (const char*)Vs[kt & 1];
        __builtin_amdgcn_s_setprio(1);
#pragma unroll
        for (int ks = 0; ks < 4; ++ks) {
            const int dl = w * 16 + lr;
            const int cv = ks * 4 + half;
            short8 bv = *(const short8*)(vbuf + dl * 256 + ((cv ^ (dl & 7)) << 4));
#pragma unroll
            for (int m = 0; m < 4; ++m) {
                short8 ae = *(const short8*)((const char*)Es + (m * 16 + lr) * 256 +
                                             ((ks * 64 + half * 16) ^ ((lr & 7) << 4)));
                ctxa[m] = __builtin_amdgcn_mfma_f32_16x16x32_bf16(ae, bv, ctxa[m], 0, 0, 0);
            }
        }
        __builtin_amdgcn_s_setprio(0);

        // P-write: 256 threads cover 64 rows x 4 chunk-groups (32 f32 each),
        // CACHED stores (r7 lesson: NT partial-line stores = 2.3x HBM write amp)
        {
            const int prow = t >> 2, pg = t & 3;
            const char* erow = (const char*)Es + prow * 256;
            const int swz = (prow & 7) << 4;
            float* drow = ab + (size_t)prow * SS + kt * 128;
#pragma unroll
            for (int c = 0; c < 4; ++c) {
                const int chunk = pg * 4 + c;
                short8 ev = *(const short8*)(erow + ((chunk * 16) ^ swz));
                float* dst = drow + chunk * 8;
                f32x4 o0, o1;
                o0[0] = bf2f((unsigned short)ev[0]); o0[1] = bf2f((unsigned short)ev[1]);
                o0[2] = bf2f((unsigned short)ev[2]); o0[3] = bf2f((unsigned short)ev[3]);
                o1[0] = bf2f((unsigned short)ev[4]); o1[1] = bf2f((unsigned short)ev[5]);
                o1[2] = bf2f((unsigned short)ev[6]); o1[3] = bf2f((unsigned short)ev[7]);
                *(f32x4*)dst = o0;
                *(f32x4*)(dst + 4) = o1;
            }
        }
        // rotate prefetched K frags
#pragma unroll
        for (int nn = 0; nn < 2; ++nn) {
            ak[nn][0] = akn[nn][0];
            ak[nn][1] = akn[nn][1];
        }
    }

    // ctx write (already normalized)
#pragma unroll
    for (int m = 0; m < 4; ++m)
#pragma unroll
        for (int j = 0; j < 4; ++j) {
            int row = m * 16 + half * 4 + j;
            cb[((size_t)b * SS + q0 + row) * DM + h * DK + w * 16 + lr] = f2bf(ctxa[m][j]);
        }
#undef STAGE_V
}

// ------- residual add (two f32 split-K partials + opt bias) + layernorm ----
__global__ __launch_bounds__(256) void add_ln_kernel(
    const float* __restrict__ p0, const float* __restrict__ p1,
    const float* __restrict__ bias, const float* __restrict__ xin,
    const float* __restrict__ g, const float* __restrict__ bta,
    float* __restrict__ xout, unsigned short* __restrict__ xbout)
{
    int row = blockIdx.x;
    int t = threadIdx.x;
    const float* a0 = p0 + (size_t)row * DM;
    const float* a1 = p1 + (size_t)row * DM;
    const float* xr = xin + (size_t)row * DM;
    float* orow = xout + (size_t)row * DM;
    unsigned short* obr = xbout + (size_t)row * DM;
    __shared__ float red[256];
    float v[3];
    float sum = 0.0f;
#pragma unroll
    for (int i = 0; i < 3; ++i) {
        int c = t + 256 * i;
        v[i] = a0[c] + a1[c] + xr[c] + (bias ? bias[c] : 0.0f);
        sum += v[i];
    }
    red[t] = sum;
    __syncthreads();
    for (int s = 128; s > 0; s >>= 1) {
        if (t < s) red[t] += red[t + s];
        __syncthreads();
    }
    float mean = red[0] * (1.0f / DM);
    __syncthreads();
    float sq = 0.0f;
#pragma unroll
    for (int i = 0; i < 3; ++i) {
        float d = v[i] - mean;
        sq += d * d;
    }
    red[t] = sq;
    __syncthreads();
    for (int s = 128; s > 0; s >>= 1) {
        if (t < s) red[t] += red[t + s];
        __syncthreads();
    }
    float inv = 1.0f / sqrtf(red[0] * (1.0f / DM) + 1e-5f);
#pragma unroll
    for (int i = 0; i < 3; ++i) {
        int c = t + 256 * i;
        float ov = (v[i] - mean) * inv * g[c] + bta[c];
        orow[c] = ov;
        obr[c] = f2bf(ov);
    }
}

extern "C" void kernel_launch(void* const* d_in, const int* in_sizes, int n_in,
                              void* d_out, int out_size, void* d_ws, size_t ws_size,
                              hipStream_t stream)
{
    const int*   toks  = (const int*)d_in[0];
    const int*   amask = (const int*)d_in[1];
    const float* emb   = (const float*)d_in[2];
    const float* pos   = (const float*)d_in[3];
    const float* wq    = (const float*)d_in[4];
    const float* wk    = (const float*)d_in[5];
    const float* wv    = (const float*)d_in[6];
    const float* wo    = (const float*)d_in[7];
    const float* ln1g  = (const float*)d_in[8];
    const float* ln1b  = (const float*)d_in[9];
    const float* w1    = (const float*)d_in[10];
    const float* b1    = (const float*)d_in[11];
    const float* w2    = (const float*)d_in[12];
    const float* b2    = (const float*)d_in[13];
    const float* ln2g  = (const float*)d_in[14];
    const float* ln2b  = (const float*)d_in[15];

    float* out = (float*)d_out;
    char*  wsb = (char*)d_ws;

    const size_t ROWS = (size_t)BB * SS;                 // 4096
    const size_t XSZ  = ROWS * DM;                       // 3,145,728
    const size_t ATTN_L = (size_t)BB * NH * SS * SS;     // 100,663,296

    float*          x    = (float*)(wsb);                          // 12.58 MB
    unsigned short* xb   = (unsigned short*)(wsb + 12582912);      // 6.29 MB
    unsigned short* qb   = (unsigned short*)(wsb + 18874368);      // 6.29 MB (QKV out 0)
    unsigned short* kbuf = (unsigned short*)(wsb + 25165824);      // 6.29 MB (QKV out 1)
    unsigned short* vb   = (unsigned short*)(wsb + 31457280);      // 6.29 MB (QKV out 2)
    unsigned short* cb   = (unsigned short*)(wsb + 37748736);      // 6.29 MB
    float*          p0   = (float*)(wsb + 44040192);               // 25.17 MB (2 split-K slabs)
    unsigned short* vt   = (unsigned short*)(wsb + 69206016);      // aliases ffb
    unsigned short* ffb  = (unsigned short*)(wsb + 69206016);      // 25.17 MB
    unsigned short* wt   = (unsigned short*)(wsb + 94371840);      // 28.31 MB (both layers)

    float* attn_out = out + XSZ;

    embed_kernel<<<ROWS, 256, 0, stream>>>(toks, emb, pos, x, xb);
    prep_weights<<<13824, 256, 0, stream>>>(wq, wk, wv, wo, w1, w2, wt);

    for (int l = 0; l < NL; ++l) {
        unsigned short* QKVT = wt + (size_t)l * 7077888;
        unsigned short* WOT  = QKVT + 1769472;
        unsigned short* W1T  = QKVT + 2359296;
        unsigned short* W2T  = QKVT + 4718592;

        // merged QKV projection: N=2304 -> qb | kbuf | vb (row-major bf16)
        gemm_bt<4><<<dim3(18, 32), 256, 0, stream>>>(xb, QKVT, nullptr, qb, DM, DM, DM, DM);
        transpose_v<<<dim3(24, 128), 256, 0, stream>>>(vb, vt);

        float* attnL = attn_out + (size_t)l * ATTN_L;
        attn_fused<<<768, 256, 0, stream>>>(qb, kbuf, vt, amask, attnL, cb);

        // output projection (split-K=2, f32 partials) + LN1
        gemm_bt<0><<<dim3(6, 32, 2), 256, 0, stream>>>(cb, WOT, nullptr, p0, 384, DM, DM, DM);
        add_ln_kernel<<<ROWS, 256, 0, stream>>>(p0, p0 + XSZ, nullptr, x,
                                                ln1g + l * DM, ln1b + l * DM, x, xb);

        // FFN: W1+relu, W2 (split-K=2) + LN2 (bias b2 folded into LN)
        gemm_bt<2><<<dim3(24, 32), 256, 0, stream>>>(xb, W1T, b1 + (size_t)l * DFF, ffb, DM, DM, DM, DFF);
        gemm_bt<0><<<dim3(6, 32, 2), 256, 0, stream>>>(ffb, W2T, nullptr, p0, 1536, DFF, DFF, DM);

        float* xdst = (l == NL - 1) ? out : x;
        add_ln_kernel<<<ROWS, 256, 0, stream>>>(p0, p0 + XSZ, b2 + (size_t)l * DM, x,
                                                ln2g + l * DM, ln2b + l * DM, xdst, xb);
    }
}